// Round 2
// baseline (6732.723 us; speedup 1.0000x reference)
//
#include <hip/hip_runtime.h>
#include <hip/hip_bf16.h>
#include <stdint.h>

// HybridQLSTM on MI355X — R2: split-K step GEMM with global_load_lds staging,
// XOR-swizzled LDS, 2-phase pipeline; x pre-converted to bf16.
//
// Per step t:
//   comb = [x_t, hx]                         [256, 2048]
//   pre  = comb @ Wall^T   (Wall rows: [enc_f@Wq | enc_i@Wq | Wu | Wo])
//   wires (sequential, per-row, 8 qubits) on zf,zi; gates; state update.
// Split-K: kh=0 covers k in [0,1024) (x part), kh=1 covers [1024,2048) (hx part).

#define T_STEPS 128
#define BATCH   256
#define DIN_    1024
#define HID_    1024
#define NQ_     8
#define DCAT    2048
#define NG      4096

using short8 = __attribute__((ext_vector_type(8))) short;
using f32x4  = __attribute__((ext_vector_type(4))) float;

static __device__ __forceinline__ ushort f2bf(float f) {
    union { float f; uint32_t u; } c{f};
    uint32_t u = c.u;
    uint32_t r = (u + 0x7fffu + ((u >> 16) & 1u)) >> 16;   // RNE
    return (ushort)r;
}
static __device__ __forceinline__ float sigmoid_fast(float x) {
    return 1.f / (1.f + __expf(-x));
}
static __device__ __forceinline__ float tanh_fast(float x) {
    float xc = fminf(fmaxf(x, -15.f), 15.f);
    float e  = __expf(-2.f * xc);
    return (1.f - e) / (1.f + e);
}
static __device__ __forceinline__ void gload_lds16(const ushort* g, ushort* l) {
    __builtin_amdgcn_global_load_lds(
        (const __attribute__((address_space(1))) void*)g,
        (__attribute__((address_space(3))) void*)l, 16, 0, 0);
}

// ---------------- precompute kernels ----------------

__global__ void quant_bf16_k(const float* __restrict__ src, ushort* __restrict__ dst, int n4) {
    int i = blockIdx.x * blockDim.x + threadIdx.x;
    if (i < n4) {
        float4 v = ((const float4*)src)[i];
        ushort4 o;
        o.x = f2bf(v.x); o.y = f2bf(v.y); o.z = f2bf(v.z); o.w = f2bf(v.w);
        ((ushort4*)dst)[i] = o;
    }
}

// Wq [1024][2048] fp32 -> WqT [2048][1024] bf16
__global__ void transpose_quant_k(const float* __restrict__ Wq, ushort* __restrict__ WqT) {
    __shared__ float tile[32][33];
    int bx = blockIdx.x, by = blockIdx.y;
    int tx = threadIdx.x, ty = threadIdx.y;
#pragma unroll
    for (int p = 0; p < 4; ++p)
        tile[ty + 8*p][tx] = Wq[(size_t)(by*32 + ty + 8*p) * 2048 + bx*32 + tx];
    __syncthreads();
#pragma unroll
    for (int p = 0; p < 4; ++p)
        WqT[(size_t)(bx*32 + ty + 8*p) * 1024 + by*32 + tx] = f2bf(tile[tx][ty + 8*p]);
}

__global__ void bias_merge_k(const float* __restrict__ enc, const float* __restrict__ bq,
                             float* __restrict__ out) {
    int j = blockIdx.x * blockDim.x + threadIdx.x;
    const float* row = enc + (size_t)j * 1024;
    float s = 0.f;
    for (int m = 0; m < 1024; m += 4) {
        float4 e = *(const float4*)(row + m);
        float4 b = *(const float4*)(bq + m);
        s += e.x*b.x + e.y*b.y + e.z*b.z + e.w*b.w;
    }
    out[j] = s;
}

// C[m][n] = sum_k A[m][k]*Bt[n][k];  A:[M][K], Bt:[N][K] bf16 -> C bf16 (one-time)
__global__ __launch_bounds__(256) void gemm_bt_ww_k(const ushort* __restrict__ A,
                                                    const ushort* __restrict__ Bt,
                                                    ushort* __restrict__ C,
                                                    int M, int N, int K) {
    __shared__ ushort As[64][72];
    __shared__ ushort Bs[64][72];
    const int tid = threadIdx.x;
    const int tile_n = blockIdx.x * 64;
    const int tile_m = blockIdx.y * 64;
    const int r8 = tid >> 3;
    const int c8 = (tid & 7) << 3;
    const int wid = tid >> 6, lane = tid & 63;
    const int wm = (wid >> 1) * 32, wn = (wid & 1) * 32;
    const int l15 = lane & 15, lk = (lane >> 4) << 3;

    f32x4 acc00 = {0,0,0,0}, acc01 = {0,0,0,0}, acc10 = {0,0,0,0}, acc11 = {0,0,0,0};

    for (int k0 = 0; k0 < K; k0 += 64) {
#pragma unroll
        for (int p = 0; p < 2; ++p) {
            int row = p*32 + r8;
            *(short8*)&As[row][c8] = *(const short8*)(A  + (size_t)(tile_m + row)*K + k0 + c8);
            *(short8*)&Bs[row][c8] = *(const short8*)(Bt + (size_t)(tile_n + row)*K + k0 + c8);
        }
        __syncthreads();
#pragma unroll
        for (int ks = 0; ks < 2; ++ks) {
            short8 a0 = *(short8*)&As[wm      + l15][ks*32 + lk];
            short8 a1 = *(short8*)&As[wm + 16 + l15][ks*32 + lk];
            short8 b0 = *(short8*)&Bs[wn      + l15][ks*32 + lk];
            short8 b1 = *(short8*)&Bs[wn + 16 + l15][ks*32 + lk];
            acc00 = __builtin_amdgcn_mfma_f32_16x16x32_bf16(a0, b0, acc00, 0, 0, 0);
            acc01 = __builtin_amdgcn_mfma_f32_16x16x32_bf16(a0, b1, acc01, 0, 0, 0);
            acc10 = __builtin_amdgcn_mfma_f32_16x16x32_bf16(a1, b0, acc10, 0, 0, 0);
            acc11 = __builtin_amdgcn_mfma_f32_16x16x32_bf16(a1, b1, acc11, 0, 0, 0);
        }
        __syncthreads();
    }
    const int orow = (lane >> 4) * 4;
#pragma unroll
    for (int r = 0; r < 4; ++r) {
        int m0 = tile_m + wm + orow + r;
        int n0 = tile_n + wn + l15;
        C[(size_t)m0*N + n0]           = f2bf(acc00[r]);
        C[(size_t)m0*N + n0 + 16]      = f2bf(acc01[r]);
        C[(size_t)(m0+16)*N + n0]      = f2bf(acc10[r]);
        C[(size_t)(m0+16)*N + n0 + 16] = f2bf(acc11[r]);
    }
}

// ---------------- per-step split-K GEMM ----------------
// grid (64 n-tiles, 4 m-tiles, 2 kh), 256 threads (4 waves, wave tile 32x32).
// LDS: 2 bufs x (A 64x64 | B 64x64) bf16, XOR-swizzled rows, staged via
// global_load_lds(16B) with inverse-swizzled global source (rule #21).
__global__ __launch_bounds__(256, 2) void step_gemm2_k(
        const ushort* __restrict__ xbf, const ushort* __restrict__ hxb,
        const ushort* __restrict__ Wall,
        float* __restrict__ pre0, float* __restrict__ pre1, int t) {
    __shared__ ushort smem[2][8192];   // 2 x 16 KiB: [0,4096) ush = A, [4096,8192) = B

    const int tid = threadIdx.x;
    const int wv = tid >> 6, ln = tid & 63;
    const int l15 = ln & 15, hk = ln >> 4;
    const int tile_n = blockIdx.x * 64;
    const int tile_m = blockIdx.y * 64;
    const int kh = blockIdx.z;

    const ushort* Asrc = kh ? (hxb + (size_t)tile_m * 1024)
                            : (xbf + ((size_t)t * BATCH + tile_m) * 1024);
    const ushort* Bsrc = Wall + (size_t)tile_n * DCAT + kh * 1024;
    float* pre = kh ? pre1 : pre0;

    const int wm = (wv >> 1) * 32, wn = (wv & 1) * 32;

    f32x4 acc[2][2] = {{{0,0,0,0},{0,0,0,0}},{{0,0,0,0},{0,0,0,0}}};

    // staging geometry: chunk c = j*4 + wv (j=0..3); c<8 -> A rows c*8..c*8+7,
    // c>=8 -> B rows (c-8)*8... ; lane covers 16B; source col XOR-swizzled.
    const int srow = ln >> 3;                 // 0..7 within chunk
    const int scol = (ln & 7) * 8;            // ushort col base
    const int scs  = scol ^ (srow << 3);      // swizzled source col (row&7 == srow)

#define STAGE(BUFI, IT)                                                          \
    do {                                                                         \
        const int kof_ = (IT) * 64;                                              \
        _Pragma("unroll")                                                        \
        for (int j = 0; j < 4; ++j) {                                            \
            const int c_ = j * 4 + wv;                                           \
            const int r_ = (c_ & 7) * 8 + srow;                                  \
            const ushort* src_ = (c_ < 8)                                        \
                ? Asrc + (size_t)r_ * 1024 + kof_ + scs                          \
                : Bsrc + (size_t)r_ * 2048 + kof_ + scs;                         \
            gload_lds16(src_, &smem[BUFI][c_ * 512]);                            \
        }                                                                        \
    } while (0)

    STAGE(0, 0);
    asm volatile("s_waitcnt vmcnt(0)" ::: "memory");
    __builtin_amdgcn_s_barrier();

    int cur = 0;
#pragma unroll 1
    for (int it = 0; it < 16; ++it) {
        if (it + 1 < 16) STAGE(cur ^ 1, it + 1);

        const ushort* buf = smem[cur];
        short8 a[2][2], b[2][2];
#pragma unroll
        for (int ks = 0; ks < 2; ++ks) {
            const int kc = ks * 32 + hk * 8;
#pragma unroll
            for (int mi = 0; mi < 2; ++mi) {
                const int r = wm + mi * 16 + l15;
                a[mi][ks] = *(const short8*)&buf[r * 64 + (kc ^ ((r & 7) << 3))];
            }
#pragma unroll
            for (int ni = 0; ni < 2; ++ni) {
                const int r = wn + ni * 16 + l15;
                b[ni][ks] = *(const short8*)&buf[4096 + r * 64 + (kc ^ ((r & 7) << 3))];
            }
        }
#pragma unroll
        for (int ks = 0; ks < 2; ++ks)
#pragma unroll
            for (int mi = 0; mi < 2; ++mi)
#pragma unroll
                for (int ni = 0; ni < 2; ++ni)
                    acc[mi][ni] = __builtin_amdgcn_mfma_f32_16x16x32_bf16(
                        a[mi][ks], b[ni][ks], acc[mi][ni], 0, 0, 0);

        asm volatile("s_waitcnt vmcnt(0)" ::: "memory");
        __builtin_amdgcn_s_barrier();
        cur ^= 1;
    }
#undef STAGE

    const int orow = hk * 4;
#pragma unroll
    for (int mi = 0; mi < 2; ++mi)
#pragma unroll
        for (int ni = 0; ni < 2; ++ni)
#pragma unroll
            for (int r = 0; r < 4; ++r) {
                int m = tile_m + wm + mi * 16 + orow + r;
                int n = tile_n + wn + ni * 16 + l15;
                pre[(size_t)m * NG + n] = acc[mi][ni][r];
            }
}

// ---------------- per-step pointwise ----------------
// 256 blocks (one per batch row) x 256 threads.
// wave 0: f-wires, wave 1: i-wires, wave 2: g, wave 3: o. Then joint update.
__global__ __launch_bounds__(256) void step_pointwise2_k(
        const float* __restrict__ pre0, const float* __restrict__ pre1,
        const float* __restrict__ wfw, const float* __restrict__ wfb,
        const float* __restrict__ wiw, const float* __restrict__ wib,
        const float* __restrict__ bu,  const float* __restrict__ bo,
        const float* __restrict__ bias_zf, const float* __restrict__ bias_zi,
        float* __restrict__ cx, ushort* __restrict__ hxb,
        float* __restrict__ dout, int t) {
    __shared__ float zbuf[2][1024];
    __shared__ float gbuf[1024];
    __shared__ float obuf[1024];
    const int b = blockIdx.x;
    const int tid = threadIdx.x;
    const int wv = tid >> 6, ln = tid & 63;

    const float* p0 = pre0 + (size_t)b * NG;
    const float* p1 = pre1 + (size_t)b * NG;

    if (wv < 2) {
        const float* bias = wv ? bias_zi : bias_zf;
        const float* ww   = wv ? wiw : wfw;
        const float* wb   = wv ? wib : wfb;
        const int off = wv * 1024;
        float z[16];
#pragma unroll
        for (int j = 0; j < 16; ++j) {
            int k = j * 64 + ln;
            z[j] = p0[off + k] + p1[off + k] + bias[k];
        }
#pragma unroll
        for (int w = 0; w < NQ_; ++w) {
            float p = 0.f;
#pragma unroll
            for (int j = 0; j < 16; ++j) p += z[j] * ww[(size_t)w * 1024 + j * 64 + ln];
#pragma unroll
            for (int o = 1; o < 64; o <<= 1) p += __shfl_xor(p, o, 64);
            float s = tanh_fast(p + wb[w]);
            if (ln == w) z[0] = s;
        }
#pragma unroll
        for (int j = 0; j < 16; ++j) zbuf[wv][j * 64 + ln] = z[j];
    } else if (wv == 2) {
#pragma unroll
        for (int j = 0; j < 16; ++j) {
            int k = j * 64 + ln;
            gbuf[k] = tanh_fast(p0[2048 + k] + p1[2048 + k] + bu[k]);
        }
    } else {
#pragma unroll
        for (int j = 0; j < 16; ++j) {
            int k = j * 64 + ln;
            obuf[k] = sigmoid_fast(p0[3072 + k] + p1[3072 + k] + bo[k]);
        }
    }
    __syncthreads();

    float* cxr = cx + (size_t)b * HID_;
#pragma unroll
    for (int e = 0; e < 4; ++e) {
        int k = e * 256 + tid;
        float f = sigmoid_fast(zbuf[0][k]);
        float i = sigmoid_fast(zbuf[1][k]);
        float c = f * cxr[k] + i * gbuf[k];
        cxr[k] = c;
        float h = obuf[k] * tanh_fast(c);
        dout[(size_t)t * BATCH * HID_ + (size_t)b * HID_ + k] = h;
        hxb[(size_t)b * HID_ + k] = f2bf(h);
        if (t == T_STEPS - 1) {
            dout[(size_t)T_STEPS * BATCH * HID_ + (size_t)b * HID_ + k] = h;
            dout[(size_t)T_STEPS * BATCH * HID_ + (size_t)BATCH * HID_ + (size_t)b * HID_ + k] = c;
        }
    }
}

// ---------------- launch ----------------
extern "C" void kernel_launch(void* const* d_in, const int* in_sizes, int n_in,
                              void* d_out, int out_size, void* d_ws, size_t ws_size,
                              hipStream_t stream) {
    const float* inputs = (const float*)d_in[0];
    const float* Wq     = (const float*)d_in[1];
    const float* bq     = (const float*)d_in[2];
    const float* enc_f  = (const float*)d_in[3];
    const float* wf_w   = (const float*)d_in[4];
    const float* wf_b   = (const float*)d_in[5];
    const float* enc_i  = (const float*)d_in[6];
    const float* wi_w   = (const float*)d_in[7];
    const float* wi_b   = (const float*)d_in[8];
    const float* Wu     = (const float*)d_in[9];
    const float* bu     = (const float*)d_in[10];
    const float* Wo     = (const float*)d_in[11];
    const float* bo     = (const float*)d_in[12];
    float* out = (float*)d_out;

    char* ws = (char*)d_ws;
    // layout (MiB offsets):
    ushort* Wall    = (ushort*)(ws);                        // 16 MiB  [4096][2048] bf16
    ushort* xbf     = (ushort*)(ws + (16u<<20));            // 64 MiB  [128][256][1024] bf16
    float*  pre0    = (float*) (ws + (80u<<20));            // 4 MiB   [256][4096] f32
    float*  pre1    = (float*) (ws + (84u<<20));            // 4 MiB
    float*  cx      = (float*) (ws + (88u<<20));            // 1 MiB
    ushort* hxb     = (ushort*)(ws + (89u<<20));            // 0.5 MiB
    float*  bias_zf = (float*) (ws + (89u<<20) + (512u<<10));          // 4 KiB
    float*  bias_zi = (float*) (ws + (89u<<20) + (512u<<10) + 4096);   // 4 KiB
    // precompute-only scratch aliases the pre0/pre1 region:
    ushort* WqT     = (ushort*)(ws + (80u<<20));            // 4 MiB [2048][1024] bf16
    ushort* encfb   = (ushort*)(ws + (84u<<20));            // 2 MiB
    ushort* encib   = (ushort*)(ws + (86u<<20));            // 2 MiB

    hipMemsetAsync(cx,  0, (size_t)BATCH*HID_*sizeof(float), stream);
    hipMemsetAsync(hxb, 0, (size_t)BATCH*HID_*sizeof(ushort), stream);

    // one-time weight prep
    quant_bf16_k<<<1024, 256, 0, stream>>>(enc_f, encfb, 1024*1024/4);
    quant_bf16_k<<<1024, 256, 0, stream>>>(enc_i, encib, 1024*1024/4);
    quant_bf16_k<<<2048, 256, 0, stream>>>(Wu, Wall + (size_t)2048*DCAT, 1024*2048/4);
    quant_bf16_k<<<2048, 256, 0, stream>>>(Wo, Wall + (size_t)3072*DCAT, 1024*2048/4);
    transpose_quant_k<<<dim3(64, 32), dim3(32, 8), 0, stream>>>(Wq, WqT);
    bias_merge_k<<<4, 256, 0, stream>>>(enc_f, bq, bias_zf);
    bias_merge_k<<<4, 256, 0, stream>>>(enc_i, bq, bias_zi);
    gemm_bt_ww_k<<<dim3(32, 16), 256, 0, stream>>>(encfb, WqT, Wall, 1024, 2048, 1024);
    gemm_bt_ww_k<<<dim3(32, 16), 256, 0, stream>>>(encib, WqT, Wall + (size_t)1024*DCAT, 1024, 2048, 1024);

    // pre-convert inputs to bf16 (after WqT use? no overlap: xbf region is separate)
    quant_bf16_k<<<32768, 256, 0, stream>>>(inputs, xbf, T_STEPS*BATCH*DIN_/4);

    for (int t = 0; t < T_STEPS; ++t) {
        step_gemm2_k<<<dim3(64, 4, 2), 256, 0, stream>>>(xbf, hxb, Wall, pre0, pre1, t);
        step_pointwise2_k<<<256, 256, 0, stream>>>(
            pre0, pre1, wf_w, wf_b, wi_w, wi_b, bu, bo, bias_zf, bias_zi,
            cx, hxb, out, t);
    }
}